// Round 3
// baseline (550.940 us; speedup 1.0000x reference)
//
#include <hip/hip_runtime.h>

#define Hm 2048
#define Em 64
#define Tm 32768
#define KSEL 640        // int(1.25 * 32768 / 64)
#define CHK 64          // k per staged chunk
#define NCHK (Hm/CHK)   // 32

typedef unsigned int u32;

__device__ __forceinline__ float4 ld4(const float* p) {
    return *reinterpret_cast<const float4*>(p);
}

// ---------------------------------------------------------------------------
// K0: W [64][2048] -> Wt [2048][64] (k-major, one-time)
// ---------------------------------------------------------------------------
__global__ __launch_bounds__(256) void k_wt(
    const float* __restrict__ W, float* __restrict__ Wt)
{
    __shared__ float T[64][65];
    const int tid = threadIdx.x;
    const int kb = blockIdx.x * 64;
    const int lc = tid & 63;
    const int lr = tid >> 6;
#pragma unroll
    for (int r = 0; r < 16; ++r) {
        const int e = r * 4 + lr;
        T[e][lc] = W[(size_t)e * Hm + kb + lc];
    }
    __syncthreads();
#pragma unroll
    for (int r = 0; r < 16; ++r) {
        const int kk = r * 4 + lr;
        Wt[(size_t)(kb + kk) * Em + lc] = T[lc][kk];
    }
}

// ---------------------------------------------------------------------------
// K1: router GEMM + softmax. grid = 512 blocks x 512 threads (8 waves).
// lane = token (64/block), wave = 8 experts, full K serial per thread.
// A: padded LDS tile [64][65] (token-major, NO transpose; pad kills the
//    32-way stride conflict). W: wave-uniform scalar loads (SGPR FMA src).
// ---------------------------------------------------------------------------
__global__ __launch_bounds__(512, 4) void k_router(
    const float* __restrict__ hid, const float* __restrict__ Wt,
    float* __restrict__ probs, float* __restrict__ probsT)
{
    __shared__ float As[64][65];     // 16.6 KB
    __shared__ float redM[8][64];    // 2 KB
    __shared__ float redS[8][64];    // 2 KB

    const int tid  = threadIdx.x;
    const int lane = tid & 63;                                    // token
    const int wid  = __builtin_amdgcn_readfirstlane(tid >> 6);    // 0..7
    const int e0   = wid * 8;                                     // expert base
    const int t0   = blockIdx.x * 64;

    // staging map: thread covers row sr (token), 8 floats at col sc
    const int sr = tid >> 3;
    const int sc = (tid & 7) * 8;
    const float* arow = hid + (size_t)(t0 + sr) * Hm + sc;

    float acc[8] = {0.f, 0.f, 0.f, 0.f, 0.f, 0.f, 0.f, 0.f};

    // prologue: stage chunk 0
    {
        const float4 p0 = ld4(arow);
        const float4 p1 = ld4(arow + 4);
        As[sr][sc + 0] = p0.x; As[sr][sc + 1] = p0.y;
        As[sr][sc + 2] = p0.z; As[sr][sc + 3] = p0.w;
        As[sr][sc + 4] = p1.x; As[sr][sc + 5] = p1.y;
        As[sr][sc + 6] = p1.z; As[sr][sc + 7] = p1.w;
    }
    __syncthreads();

    for (int c = 0; c < NCHK; ++c) {
        float4 n0, n1;
        if (c + 1 < NCHK) {              // prefetch next chunk (regs)
            n0 = ld4(arow + (c + 1) * CHK);
            n1 = ld4(arow + (c + 1) * CHK + 4);
        }

        const float* wk = Wt + (size_t)c * CHK * Em + e0;   // uniform
#pragma unroll
        for (int kk = 0; kk < CHK; kk += 2) {
            const float a0 = As[lane][kk];
            const float a1 = As[lane][kk + 1];
            const float* w0 = wk + (size_t)kk * Em;
#pragma unroll
            for (int q = 0; q < 8; ++q) {
                acc[q] = fmaf(a0, w0[q],      acc[q]);
                acc[q] = fmaf(a1, w0[Em + q], acc[q]);
            }
        }
        __syncthreads();
        if (c + 1 < NCHK) {
            As[sr][sc + 0] = n0.x; As[sr][sc + 1] = n0.y;
            As[sr][sc + 2] = n0.z; As[sr][sc + 3] = n0.w;
            As[sr][sc + 4] = n1.x; As[sr][sc + 5] = n1.y;
            As[sr][sc + 6] = n1.z; As[sr][sc + 7] = n1.w;
            __syncthreads();
        }
    }

    // ---- softmax across 8 waves (64 experts), token = lane ----
    float m = acc[0];
#pragma unroll
    for (int q = 1; q < 8; ++q) m = fmaxf(m, acc[q]);
    redM[wid][lane] = m;
    __syncthreads();
    float M = redM[0][lane];
#pragma unroll
    for (int w = 1; w < 8; ++w) M = fmaxf(M, redM[w][lane]);

    float p[8];
    float s = 0.f;
#pragma unroll
    for (int q = 0; q < 8; ++q) { p[q] = __expf(acc[q] - M); s += p[q]; }
    redS[wid][lane] = s;
    __syncthreads();
    float S = redS[0][lane];
#pragma unroll
    for (int w = 1; w < 8; ++w) S += redS[w][lane];
    const float inv = 1.0f / S;
#pragma unroll
    for (int q = 0; q < 8; ++q) p[q] *= inv;

    // probsT [E][T]: coalesced (lane = token)
    if (probsT) {
#pragma unroll
        for (int q = 0; q < 8; ++q)
            probsT[(size_t)(e0 + q) * Tm + t0 + lane] = p[q];
    }

    // probs [T][E] via LDS transpose (As is free after the loop barrier)
#pragma unroll
    for (int q = 0; q < 8; ++q) As[lane][e0 + q] = p[q];
    __syncthreads();
    {
        const int orow = tid >> 3;
        const int oc   = (tid & 7) * 8;
        const float4 o0 = make_float4(As[orow][oc + 0], As[orow][oc + 1],
                                      As[orow][oc + 2], As[orow][oc + 3]);
        const float4 o1 = make_float4(As[orow][oc + 4], As[orow][oc + 5],
                                      As[orow][oc + 6], As[orow][oc + 7]);
        float* po = probs + (size_t)(t0 + orow) * Em + oc;
        *reinterpret_cast<float4*>(po)     = o0;
        *reinterpret_cast<float4*>(po + 4) = o1;
    }
}

// ---------------------------------------------------------------------------
// K2: per-expert top-640 radix select (10/11/11 bits).
// If dT != null: write full coalesced rows dT[e][t] (no pre-zero needed).
// Else: scatter into pre-zeroed dispatch [T][E].
// ---------------------------------------------------------------------------
__device__ __forceinline__ void suffix_scan(u32* h, int nbins) {
    const int tid = threadIdx.x;
    for (int off = 1; off < nbins; off <<= 1) {
        u32 v0 = 0, v1 = 0;
        const int b0 = tid, b1 = tid + 1024;
        if (b0 < nbins) v0 = h[b0] + ((b0 + off) < nbins ? h[b0 + off] : 0u);
        if (b1 < nbins) v1 = h[b1] + ((b1 + off) < nbins ? h[b1 + off] : 0u);
        __syncthreads();
        if (b0 < nbins) h[b0] = v0;
        if (b1 < nbins) h[b1] = v1;
        __syncthreads();
    }
}

__global__ __launch_bounds__(1024) void k_select(
    const float* __restrict__ probsT, const float* __restrict__ probsRM,
    float* __restrict__ dispatch, float* __restrict__ dT)
{
    __shared__ u32 keys[Tm];        // 128 KB
    __shared__ u32 hist[2048];      // 8 KB (reused as tie list)
    __shared__ u32 sh_need[4];
    __shared__ u32 sh_bins[3];
    __shared__ u32 sh_ntie, sh_take, sh_nlist;

    const int tid = threadIdx.x;
    const int e = blockIdx.x;

    if (probsT) {
        const float4* src = reinterpret_cast<const float4*>(probsT + (size_t)e * Tm);
        for (int i = tid; i < Tm / 4; i += 1024) {
            float4 x = src[i];
            uint4 kk = make_uint4(__float_as_uint(x.x), __float_as_uint(x.y),
                                  __float_as_uint(x.z), __float_as_uint(x.w));
            *reinterpret_cast<uint4*>(&keys[4 * i]) = kk;
        }
    } else {
        for (int t = tid; t < Tm; t += 1024)
            keys[t] = __float_as_uint(probsRM[(size_t)t * Em + e]);
    }

    // pass 1: bits [31:22]
    hist[tid] = 0;
    if (tid == 0) sh_need[0] = KSEL;
    __syncthreads();
    for (int t = tid; t < Tm; t += 1024)
        atomicAdd(&hist[keys[t] >> 22], 1u);
    __syncthreads();
    suffix_scan(hist, 1024);
    {
        const u32 need = sh_need[0];
        if (tid < 1024) {
            const u32 sb = hist[tid];
            const u32 sa = (tid + 1 < 1024) ? hist[tid + 1] : 0u;
            if (sb >= need && sa < need) { sh_bins[0] = (u32)tid; sh_need[1] = need - sa; }
        }
    }
    __syncthreads();
    const u32 b1 = sh_bins[0];

    // pass 2: bits [21:11]
    hist[tid] = 0; hist[tid + 1024] = 0;
    __syncthreads();
    for (int t = tid; t < Tm; t += 1024) {
        const u32 k = keys[t];
        if ((k >> 22) == b1) atomicAdd(&hist[(k >> 11) & 0x7FFu], 1u);
    }
    __syncthreads();
    suffix_scan(hist, 2048);
    {
        const u32 need = sh_need[1];
#pragma unroll
        for (int r = 0; r < 2; ++r) {
            const int b = tid + r * 1024;
            const u32 sb = hist[b];
            const u32 sa = (b + 1 < 2048) ? hist[b + 1] : 0u;
            if (sb >= need && sa < need) { sh_bins[1] = (u32)b; sh_need[2] = need - sa; }
        }
    }
    __syncthreads();
    const u32 p2 = (b1 << 11) | sh_bins[1];

    // pass 3: bits [10:0]
    hist[tid] = 0; hist[tid + 1024] = 0;
    __syncthreads();
    for (int t = tid; t < Tm; t += 1024) {
        const u32 k = keys[t];
        if ((k >> 11) == p2) atomicAdd(&hist[k & 0x7FFu], 1u);
    }
    __syncthreads();
    suffix_scan(hist, 2048);
    {
        const u32 need = sh_need[2];
#pragma unroll
        for (int r = 0; r < 2; ++r) {
            const int b = tid + r * 1024;
            const u32 sb = hist[b];
            const u32 sa = (b + 1 < 2048) ? hist[b + 1] : 0u;
            if (sb >= need && sa < need) {
                sh_bins[2] = (u32)b;
                sh_take = need - sa;
                sh_ntie = sb - sa;
            }
        }
    }
    __syncthreads();
    const u32 Kstar = (p2 << 11) | sh_bins[2];
    const u32 take = sh_take, ntie = sh_ntie;

    if (dT) {
        float* drow = dT + (size_t)e * Tm;
        if (ntie == take) {
            for (int t = tid; t < Tm; t += 1024) {
                const u32 k = keys[t];
                drow[t] = (k >= Kstar) ? __uint_as_float(k) : 0.f;
            }
        } else {
            if (tid == 0) sh_nlist = 0;
            __syncthreads();
            for (int t = tid; t < Tm; t += 1024) {
                const u32 k = keys[t];
                drow[t] = (k > Kstar) ? __uint_as_float(k) : 0.f;
                if (k == Kstar) {
                    const u32 idx = atomicAdd(&sh_nlist, 1u);
                    if (idx < 2048u) hist[idx] = (u32)t;
                }
            }
            __syncthreads();
            const int n = (int)(sh_nlist < 2048u ? sh_nlist : 2048u);
            for (int i = tid; i < n; i += 1024) {
                const u32 t = hist[i];
                int r = 0;
                for (int j = 0; j < n; ++j) r += (hist[j] < t);
                if (r < (int)take) drow[t] = __uint_as_float(Kstar);
            }
        }
    } else {
        if (ntie == take) {
            for (int t = tid; t < Tm; t += 1024) {
                const u32 k = keys[t];
                if (k >= Kstar) dispatch[(size_t)t * Em + e] = __uint_as_float(k);
            }
        } else {
            if (tid == 0) sh_nlist = 0;
            __syncthreads();
            for (int t = tid; t < Tm; t += 1024) {
                const u32 k = keys[t];
                if (k > Kstar) {
                    dispatch[(size_t)t * Em + e] = __uint_as_float(k);
                } else if (k == Kstar) {
                    const u32 idx = atomicAdd(&sh_nlist, 1u);
                    if (idx < 2048u) hist[idx] = (u32)t;
                }
            }
            __syncthreads();
            const int n = (int)(sh_nlist < 2048u ? sh_nlist : 2048u);
            for (int i = tid; i < n; i += 1024) {
                const u32 t = hist[i];
                int r = 0;
                for (int j = 0; j < n; ++j) r += (hist[j] < t);
                if (r < (int)take)
                    dispatch[(size_t)t * Em + e] = __uint_as_float(Kstar);
            }
        }
    }
}

// ---------------------------------------------------------------------------
// K3a (dT path): transpose dT [E][T] -> dispatch [T][E] + combine, fused.
// grid = 512 blocks x 256 threads; 64 tokens per block.
// ---------------------------------------------------------------------------
__global__ __launch_bounds__(256) void k_finish(
    const float* __restrict__ dT, float* __restrict__ dispatch,
    float* __restrict__ combine)
{
    __shared__ float Ls[64][65];
    const int tid = threadIdx.x;
    const int t0 = blockIdx.x * 64;
    {
        const int e = tid >> 2, tq = tid & 3;
        const float* src = dT + (size_t)e * Tm + t0 + tq * 16;
#pragma unroll
        for (int u = 0; u < 4; ++u) {
            const float4 x = ld4(src + 4 * u);
            Ls[tq * 16 + 4 * u + 0][e] = x.x;
            Ls[tq * 16 + 4 * u + 1][e] = x.y;
            Ls[tq * 16 + 4 * u + 2][e] = x.z;
            Ls[tq * 16 + 4 * u + 3][e] = x.w;
        }
    }
    __syncthreads();
    const int t = tid >> 2, q = tid & 3;
    float v[16];
    float s = 0.f;
#pragma unroll
    for (int u = 0; u < 16; ++u) { v[u] = Ls[t][q * 16 + u]; s += v[u]; }
    s += __shfl_xor(s, 1, 4);
    s += __shfl_xor(s, 2, 4);
    const float inv = (s > 0.f) ? 1.0f / s : 0.f;
    float* dp = dispatch + (size_t)(t0 + t) * Em + q * 16;
    float* cb = combine  + (size_t)(t0 + t) * Em + q * 16;
#pragma unroll
    for (int u = 0; u < 4; ++u) {
        *reinterpret_cast<float4*>(dp + 4 * u) =
            make_float4(v[4 * u], v[4 * u + 1], v[4 * u + 2], v[4 * u + 3]);
        *reinterpret_cast<float4*>(cb + 4 * u) =
            make_float4(v[4 * u] * inv, v[4 * u + 1] * inv,
                        v[4 * u + 2] * inv, v[4 * u + 3] * inv);
    }
}

// ---------------------------------------------------------------------------
// K3b (fallback): combine from dispatch rows.
// ---------------------------------------------------------------------------
__global__ __launch_bounds__(256) void k_combine(
    const float* __restrict__ dispatch, float* __restrict__ combine)
{
    const int wid = threadIdx.x >> 6;
    const int lane = threadIdx.x & 63;
    const int t = blockIdx.x * 4 + wid;
    const float d = dispatch[(size_t)t * Em + lane];
    float s = d;
#pragma unroll
    for (int off = 32; off > 0; off >>= 1) s += __shfl_xor(s, off, 64);
    combine[(size_t)t * Em + lane] = (s > 0.f) ? d / s : 0.f;
}

// ---------------------------------------------------------------------------
extern "C" void kernel_launch(void* const* d_in, const int* in_sizes, int n_in,
                              void* d_out, int out_size, void* d_ws, size_t ws_size,
                              hipStream_t stream) {
    const float* hid = (const float*)d_in[0];
    const float* W   = (const float*)d_in[1];
    float* out      = (float*)d_out;
    float* dispatch = out;
    float* combine  = out + (size_t)Tm * Em;
    float* probs    = out + 2 * (size_t)Tm * Em;

    const size_t wtB = sizeof(float) * (size_t)Hm * Em;   // 512 KB
    const size_t teB = sizeof(float) * (size_t)Tm * Em;   // 8 MB
    char* ws = (char*)d_ws;

    float* Wt = (float*)ws;
    float* probsT = nullptr;
    float* dT = nullptr;
    if (ws_size >= wtB + teB)       probsT = (float*)(ws + wtB);
    if (ws_size >= wtB + 2 * teB)   dT     = (float*)(ws + wtB + teB);

    if (!dT)
        hipMemsetAsync(dispatch, 0, teB, stream);

    k_wt<<<Hm / 64, 256, 0, stream>>>(W, Wt);
    k_router<<<Tm / 64, 512, 0, stream>>>(hid, Wt, probs, probsT);
    k_select<<<Em, 1024, 0, stream>>>(probsT, probs, dispatch, dT);
    if (dT) k_finish<<<Tm / 64, 256, 0, stream>>>(dT, dispatch, combine);
    else    k_combine<<<Tm / 4, 256, 0, stream>>>(dispatch, combine);
}

// Round 4
// 206.487 us; speedup vs baseline: 2.6682x; 2.6682x over previous
//
#include <hip/hip_runtime.h>

#define Hm 2048
#define Em 64
#define Tm 32768
#define KSEL 640        // int(1.25 * 32768 / 64)
#define CHK 64          // k per staged chunk
#define NCHK (Hm/CHK)   // 32

typedef unsigned int u32;

__device__ __forceinline__ float4 ld4(const float* p) {
    return *reinterpret_cast<const float4*>(p);
}

// ---------------------------------------------------------------------------
// K0: W [64][2048] -> Wt [2048][64] (k-major, one-time)
// ---------------------------------------------------------------------------
__global__ __launch_bounds__(256) void k_wt(
    const float* __restrict__ W, float* __restrict__ Wt)
{
    __shared__ float T[64][65];
    const int tid = threadIdx.x;
    const int kb = blockIdx.x * 64;
    const int lc = tid & 63;
    const int lr = tid >> 6;
#pragma unroll
    for (int r = 0; r < 16; ++r) {
        const int e = r * 4 + lr;
        T[e][lc] = W[(size_t)e * Hm + kb + lc];
    }
    __syncthreads();
#pragma unroll
    for (int r = 0; r < 16; ++r) {
        const int kk = r * 4 + lr;
        Wt[(size_t)(kb + kk) * Em + lc] = T[lc][kk];
    }
}

// ---------------------------------------------------------------------------
// K1: router GEMM + softmax. grid = 1024 blocks x 256 threads (4 waves).
// Wave = 8 tokens x 64 experts; thread tile = 1 token x 8 experts.
// LDS reads are broadcast-heavy: A-read shared by 8 lanes (expert octets),
// B-read shared by 8 lanes (token octets) -> LDS pipe ~45% at full FMA issue.
// A-tile token-major [32][68] (pad 68 -> conflict-free b128 reads, direct
// float4 staging, NO transpose). B-tile k-major [64][68] from Wt.
// ---------------------------------------------------------------------------
__global__ __launch_bounds__(256, 4) void k_router(
    const float* __restrict__ hid, const float* __restrict__ Wt,
    float* __restrict__ probs, float* __restrict__ probsT)
{
    __shared__ float As[32][68];     // 8.7 KB
    __shared__ float Bs[CHK][68];    // 17.4 KB

    const int tid  = threadIdx.x;
    const int lane = tid & 63;
    const int w    = tid >> 6;        // wave 0..3
    const int tokl = lane & 7;        // token within wave
    const int eg   = lane >> 3;       // expert octet 0..7
    const int e0   = eg * 8;
    const int t0   = blockIdx.x * 32;
    const int arow = w * 8 + tokl;    // A-tile row this thread computes

    // staging map: thread loads A row sr, 8 floats at col sc (coalesced)
    const int sr = tid >> 3;          // 0..31
    const int sc = (tid & 7) * 8;     // 0..56
    const float* ap = hid + (size_t)(t0 + sr) * Hm + sc;

    float acc[8] = {0.f, 0.f, 0.f, 0.f, 0.f, 0.f, 0.f, 0.f};

    // prologue: stage chunk 0
    {
        const float4 a0 = ld4(ap), a1 = ld4(ap + 4);
        const float* bp = Wt + 4 * tid;
        const float4 b0 = ld4(bp), b1 = ld4(bp + 1024),
                     b2 = ld4(bp + 2048), b3 = ld4(bp + 3072);
        *reinterpret_cast<float4*>(&As[sr][sc])     = a0;
        *reinterpret_cast<float4*>(&As[sr][sc + 4]) = a1;
        const int F = 4 * tid;
        *reinterpret_cast<float4*>(&Bs[(F) >> 6][(F) & 63])               = b0;
        *reinterpret_cast<float4*>(&Bs[(F + 1024) >> 6][(F + 1024) & 63]) = b1;
        *reinterpret_cast<float4*>(&Bs[(F + 2048) >> 6][(F + 2048) & 63]) = b2;
        *reinterpret_cast<float4*>(&Bs[(F + 3072) >> 6][(F + 3072) & 63]) = b3;
    }
    __syncthreads();

    for (int c = 0; c < NCHK; ++c) {
        float4 na0, na1, nb0, nb1, nb2, nb3;
        if (c + 1 < NCHK) {           // prefetch next chunk into regs
            const float* ap2 = ap + (c + 1) * CHK;
            na0 = ld4(ap2); na1 = ld4(ap2 + 4);
            const float* bp2 = Wt + (size_t)(c + 1) * (CHK * Em) + 4 * tid;
            nb0 = ld4(bp2);        nb1 = ld4(bp2 + 1024);
            nb2 = ld4(bp2 + 2048); nb3 = ld4(bp2 + 3072);
        }

#pragma unroll 2
        for (int kk = 0; kk < CHK; kk += 4) {
            const float4 av = ld4(&As[arow][kk]);
            const float a4[4] = { av.x, av.y, av.z, av.w };
#pragma unroll
            for (int u = 0; u < 4; ++u) {
                const float4 b0 = ld4(&Bs[kk + u][e0]);
                const float4 b1 = ld4(&Bs[kk + u][e0 + 4]);
                acc[0] = fmaf(a4[u], b0.x, acc[0]);
                acc[1] = fmaf(a4[u], b0.y, acc[1]);
                acc[2] = fmaf(a4[u], b0.z, acc[2]);
                acc[3] = fmaf(a4[u], b0.w, acc[3]);
                acc[4] = fmaf(a4[u], b1.x, acc[4]);
                acc[5] = fmaf(a4[u], b1.y, acc[5]);
                acc[6] = fmaf(a4[u], b1.z, acc[6]);
                acc[7] = fmaf(a4[u], b1.w, acc[7]);
            }
        }
        __syncthreads();
        if (c + 1 < NCHK) {
            *reinterpret_cast<float4*>(&As[sr][sc])     = na0;
            *reinterpret_cast<float4*>(&As[sr][sc + 4]) = na1;
            const int F = 4 * tid;
            *reinterpret_cast<float4*>(&Bs[(F) >> 6][(F) & 63])               = nb0;
            *reinterpret_cast<float4*>(&Bs[(F + 1024) >> 6][(F + 1024) & 63]) = nb1;
            *reinterpret_cast<float4*>(&Bs[(F + 2048) >> 6][(F + 2048) & 63]) = nb2;
            *reinterpret_cast<float4*>(&Bs[(F + 3072) >> 6][(F + 3072) & 63]) = nb3;
            __syncthreads();
        }
    }

    // ---- softmax: 64 experts of token t live in 8 lanes (eg = lane>>3) ----
    float m = acc[0];
#pragma unroll
    for (int j = 1; j < 8; ++j) m = fmaxf(m, acc[j]);
    m = fmaxf(m, __shfl_xor(m, 8, 64));
    m = fmaxf(m, __shfl_xor(m, 16, 64));
    m = fmaxf(m, __shfl_xor(m, 32, 64));

    float p[8];
    float s = 0.f;
#pragma unroll
    for (int j = 0; j < 8; ++j) { p[j] = __expf(acc[j] - m); s += p[j]; }
    s += __shfl_xor(s, 8, 64);
    s += __shfl_xor(s, 16, 64);
    s += __shfl_xor(s, 32, 64);
    const float inv = 1.0f / s;
#pragma unroll
    for (int j = 0; j < 8; ++j) p[j] *= inv;

    const int t = t0 + arow;
    if (probsT) {
#pragma unroll
        for (int j = 0; j < 8; ++j)
            probsT[(size_t)(e0 + j) * Tm + t] = p[j];
    }
    float* po = probs + (size_t)t * Em + e0;
    *reinterpret_cast<float4*>(po)     = make_float4(p[0], p[1], p[2], p[3]);
    *reinterpret_cast<float4*>(po + 4) = make_float4(p[4], p[5], p[6], p[7]);
}

// ---------------------------------------------------------------------------
// K2: per-expert top-640 radix select (10/11/11 bits).
// dT path: write full coalesced rows dT[e][t] (no pre-zero needed).
// ---------------------------------------------------------------------------
__device__ __forceinline__ void suffix_scan(u32* h, int nbins) {
    const int tid = threadIdx.x;
    for (int off = 1; off < nbins; off <<= 1) {
        u32 v0 = 0, v1 = 0;
        const int b0 = tid, b1 = tid + 1024;
        if (b0 < nbins) v0 = h[b0] + ((b0 + off) < nbins ? h[b0 + off] : 0u);
        if (b1 < nbins) v1 = h[b1] + ((b1 + off) < nbins ? h[b1 + off] : 0u);
        __syncthreads();
        if (b0 < nbins) h[b0] = v0;
        if (b1 < nbins) h[b1] = v1;
        __syncthreads();
    }
}

__global__ __launch_bounds__(1024) void k_select(
    const float* __restrict__ probsT, const float* __restrict__ probsRM,
    float* __restrict__ dispatch, float* __restrict__ dT)
{
    __shared__ u32 keys[Tm];        // 128 KB
    __shared__ u32 hist[2048];      // 8 KB (reused as tie list)
    __shared__ u32 sh_need[4];
    __shared__ u32 sh_bins[3];
    __shared__ u32 sh_ntie, sh_take, sh_nlist;

    const int tid = threadIdx.x;
    const int e = blockIdx.x;

    if (probsT) {
        const float4* src = reinterpret_cast<const float4*>(probsT + (size_t)e * Tm);
        for (int i = tid; i < Tm / 4; i += 1024) {
            float4 x = src[i];
            uint4 kk = make_uint4(__float_as_uint(x.x), __float_as_uint(x.y),
                                  __float_as_uint(x.z), __float_as_uint(x.w));
            *reinterpret_cast<uint4*>(&keys[4 * i]) = kk;
        }
    } else {
        for (int t = tid; t < Tm; t += 1024)
            keys[t] = __float_as_uint(probsRM[(size_t)t * Em + e]);
    }

    // pass 1: bits [31:22]
    hist[tid] = 0;
    if (tid == 0) sh_need[0] = KSEL;
    __syncthreads();
    for (int t = tid; t < Tm; t += 1024)
        atomicAdd(&hist[keys[t] >> 22], 1u);
    __syncthreads();
    suffix_scan(hist, 1024);
    {
        const u32 need = sh_need[0];
        if (tid < 1024) {
            const u32 sb = hist[tid];
            const u32 sa = (tid + 1 < 1024) ? hist[tid + 1] : 0u;
            if (sb >= need && sa < need) { sh_bins[0] = (u32)tid; sh_need[1] = need - sa; }
        }
    }
    __syncthreads();
    const u32 b1 = sh_bins[0];

    // pass 2: bits [21:11]
    hist[tid] = 0; hist[tid + 1024] = 0;
    __syncthreads();
    for (int t = tid; t < Tm; t += 1024) {
        const u32 k = keys[t];
        if ((k >> 22) == b1) atomicAdd(&hist[(k >> 11) & 0x7FFu], 1u);
    }
    __syncthreads();
    suffix_scan(hist, 2048);
    {
        const u32 need = sh_need[1];
#pragma unroll
        for (int r = 0; r < 2; ++r) {
            const int b = tid + r * 1024;
            const u32 sb = hist[b];
            const u32 sa = (b + 1 < 2048) ? hist[b + 1] : 0u;
            if (sb >= need && sa < need) { sh_bins[1] = (u32)b; sh_need[2] = need - sa; }
        }
    }
    __syncthreads();
    const u32 p2 = (b1 << 11) | sh_bins[1];

    // pass 3: bits [10:0]
    hist[tid] = 0; hist[tid + 1024] = 0;
    __syncthreads();
    for (int t = tid; t < Tm; t += 1024) {
        const u32 k = keys[t];
        if ((k >> 11) == p2) atomicAdd(&hist[k & 0x7FFu], 1u);
    }
    __syncthreads();
    suffix_scan(hist, 2048);
    {
        const u32 need = sh_need[2];
#pragma unroll
        for (int r = 0; r < 2; ++r) {
            const int b = tid + r * 1024;
            const u32 sb = hist[b];
            const u32 sa = (b + 1 < 2048) ? hist[b + 1] : 0u;
            if (sb >= need && sa < need) {
                sh_bins[2] = (u32)b;
                sh_take = need - sa;
                sh_ntie = sb - sa;
            }
        }
    }
    __syncthreads();
    const u32 Kstar = (p2 << 11) | sh_bins[2];
    const u32 take = sh_take, ntie = sh_ntie;

    if (dT) {
        float* drow = dT + (size_t)e * Tm;
        if (ntie == take) {
            for (int t = tid; t < Tm; t += 1024) {
                const u32 k = keys[t];
                drow[t] = (k >= Kstar) ? __uint_as_float(k) : 0.f;
            }
        } else {
            if (tid == 0) sh_nlist = 0;
            __syncthreads();
            for (int t = tid; t < Tm; t += 1024) {
                const u32 k = keys[t];
                drow[t] = (k > Kstar) ? __uint_as_float(k) : 0.f;
                if (k == Kstar) {
                    const u32 idx = atomicAdd(&sh_nlist, 1u);
                    if (idx < 2048u) hist[idx] = (u32)t;
                }
            }
            __syncthreads();
            const int n = (int)(sh_nlist < 2048u ? sh_nlist : 2048u);
            for (int i = tid; i < n; i += 1024) {
                const u32 t = hist[i];
                int r = 0;
                for (int j = 0; j < n; ++j) r += (hist[j] < t);
                if (r < (int)take) drow[t] = __uint_as_float(Kstar);
            }
        }
    } else {
        if (ntie == take) {
            for (int t = tid; t < Tm; t += 1024) {
                const u32 k = keys[t];
                if (k >= Kstar) dispatch[(size_t)t * Em + e] = __uint_as_float(k);
            }
        } else {
            if (tid == 0) sh_nlist = 0;
            __syncthreads();
            for (int t = tid; t < Tm; t += 1024) {
                const u32 k = keys[t];
                if (k > Kstar) {
                    dispatch[(size_t)t * Em + e] = __uint_as_float(k);
                } else if (k == Kstar) {
                    const u32 idx = atomicAdd(&sh_nlist, 1u);
                    if (idx < 2048u) hist[idx] = (u32)t;
                }
            }
            __syncthreads();
            const int n = (int)(sh_nlist < 2048u ? sh_nlist : 2048u);
            for (int i = tid; i < n; i += 1024) {
                const u32 t = hist[i];
                int r = 0;
                for (int j = 0; j < n; ++j) r += (hist[j] < t);
                if (r < (int)take)
                    dispatch[(size_t)t * Em + e] = __uint_as_float(Kstar);
            }
        }
    }
}

// ---------------------------------------------------------------------------
// K3a (dT path): transpose dT [E][T] -> dispatch [T][E] + combine, fused.
// ---------------------------------------------------------------------------
__global__ __launch_bounds__(256) void k_finish(
    const float* __restrict__ dT, float* __restrict__ dispatch,
    float* __restrict__ combine)
{
    __shared__ float Ls[64][65];
    const int tid = threadIdx.x;
    const int t0 = blockIdx.x * 64;
    {
        const int e = tid >> 2, tq = tid & 3;
        const float* src = dT + (size_t)e * Tm + t0 + tq * 16;
#pragma unroll
        for (int u = 0; u < 4; ++u) {
            const float4 x = ld4(src + 4 * u);
            Ls[tq * 16 + 4 * u + 0][e] = x.x;
            Ls[tq * 16 + 4 * u + 1][e] = x.y;
            Ls[tq * 16 + 4 * u + 2][e] = x.z;
            Ls[tq * 16 + 4 * u + 3][e] = x.w;
        }
    }
    __syncthreads();
    const int t = tid >> 2, q = tid & 3;
    float v[16];
    float s = 0.f;
#pragma unroll
    for (int u = 0; u < 16; ++u) { v[u] = Ls[t][q * 16 + u]; s += v[u]; }
    s += __shfl_xor(s, 1, 4);
    s += __shfl_xor(s, 2, 4);
    const float inv = (s > 0.f) ? 1.0f / s : 0.f;
    float* dp = dispatch + (size_t)(t0 + t) * Em + q * 16;
    float* cb = combine  + (size_t)(t0 + t) * Em + q * 16;
#pragma unroll
    for (int u = 0; u < 4; ++u) {
        *reinterpret_cast<float4*>(dp + 4 * u) =
            make_float4(v[4 * u], v[4 * u + 1], v[4 * u + 2], v[4 * u + 3]);
        *reinterpret_cast<float4*>(cb + 4 * u) =
            make_float4(v[4 * u] * inv, v[4 * u + 1] * inv,
                        v[4 * u + 2] * inv, v[4 * u + 3] * inv);
    }
}

// ---------------------------------------------------------------------------
// K3b (fallback): combine from dispatch rows.
// ---------------------------------------------------------------------------
__global__ __launch_bounds__(256) void k_combine(
    const float* __restrict__ dispatch, float* __restrict__ combine)
{
    const int wid = threadIdx.x >> 6;
    const int lane = threadIdx.x & 63;
    const int t = blockIdx.x * 4 + wid;
    const float d = dispatch[(size_t)t * Em + lane];
    float s = d;
#pragma unroll
    for (int off = 32; off > 0; off >>= 1) s += __shfl_xor(s, off, 64);
    combine[(size_t)t * Em + lane] = (s > 0.f) ? d / s : 0.f;
}

// ---------------------------------------------------------------------------
extern "C" void kernel_launch(void* const* d_in, const int* in_sizes, int n_in,
                              void* d_out, int out_size, void* d_ws, size_t ws_size,
                              hipStream_t stream) {
    const float* hid = (const float*)d_in[0];
    const float* W   = (const float*)d_in[1];
    float* out      = (float*)d_out;
    float* dispatch = out;
    float* combine  = out + (size_t)Tm * Em;
    float* probs    = out + 2 * (size_t)Tm * Em;

    const size_t wtB = sizeof(float) * (size_t)Hm * Em;   // 512 KB
    const size_t teB = sizeof(float) * (size_t)Tm * Em;   // 8 MB
    char* ws = (char*)d_ws;

    float* Wt = (float*)ws;
    float* probsT = nullptr;
    float* dT = nullptr;
    if (ws_size >= wtB + teB)       probsT = (float*)(ws + wtB);
    if (ws_size >= wtB + 2 * teB)   dT     = (float*)(ws + wtB + teB);

    if (!dT)
        hipMemsetAsync(dispatch, 0, teB, stream);

    k_wt<<<Hm / 64, 256, 0, stream>>>(W, Wt);
    k_router<<<Tm / 32, 256, 0, stream>>>(hid, Wt, probs, probsT);
    k_select<<<Em, 1024, 0, stream>>>(probsT, probs, dispatch, dT);
    if (dT) k_finish<<<Tm / 64, 256, 0, stream>>>(dT, dispatch, combine);
    else    k_combine<<<Tm / 4, 256, 0, stream>>>(dispatch, combine);
}